// Round 5
// baseline (551.400 us; speedup 1.0000x reference)
//
#include <hip/hip_runtime.h>
#include <hip/hip_bf16.h>

// TopKPool: N=8192 nodes, F=256 features, k=4096 kept.
// out = [X_pooled (4096x256 f32) | A_pooled (4096x4096 f32)]
// A_pooled = A[idx,:] @ A[:,idx] (0.275 TFLOP) instead of (A@A)[idx][:,idx].
// Round 8: gemm K-slab 64B -> 128B. R7 made MFMA(1100cy) ~ LDS(1000cy) per
// slab; residual is per-slab fixed cost (2 barriers + vmcnt gate + lgkm
// drain) fully exposed at 1 block/CU. Doubling the slab halves that fraction.
// Ring-2 x 64KB slots = 128KB LDS. Compute phased per K-half (12 b128 reads
// -> 8 MFMA) to keep VGPR <= 256. Swizzle: 8 subchunks/row, s' = s ^ (row&7)
// (same involution on staging source and ds_read; 8 consecutive rows cover
// all 8 bank-quads). Only gemm_fp8 changed vs the 550.5us build.

#define N_NODES 8192
#define F_DIM   256
#define K_SEL   4096

typedef float floatx4  __attribute__((ext_vector_type(4)));
typedef float floatx16 __attribute__((ext_vector_type(16)));
typedef int   intx4    __attribute__((ext_vector_type(4)));
typedef int   intx8    __attribute__((ext_vector_type(8)));

__device__ __forceinline__ void async_copy16(const void* g, void* l) {
  __builtin_amdgcn_global_load_lds((const __attribute__((address_space(1))) void*)g,
                                   (__attribute__((address_space(3))) void*)l,
                                   16, 0, 0);
}

// ---------------- y = X @ (p / ||p||) : one wave per row ----------------
__global__ __launch_bounds__(256) void compute_y(const float* __restrict__ X,
                                                 const float* __restrict__ p,
                                                 float* __restrict__ y) {
  __shared__ __align__(16) float s_p[F_DIM];
  __shared__ float s_part[4];
  __shared__ float s_inv;
  const int tid = threadIdx.x;
  float pv = p[tid];
  s_p[tid] = pv;
  float sq = pv * pv;
  #pragma unroll
  for (int off = 32; off > 0; off >>= 1) sq += __shfl_down(sq, off, 64);
  if ((tid & 63) == 0) s_part[tid >> 6] = sq;
  __syncthreads();
  if (tid == 0) s_inv = rsqrtf(s_part[0] + s_part[1] + s_part[2] + s_part[3]);
  __syncthreads();
  const int wave = tid >> 6, lane = tid & 63;
  const int row = blockIdx.x * 4 + wave;
  const float4* xr = (const float4*)(X + (size_t)row * F_DIM);
  const float4* pr = (const float4*)s_p;
  float4 xv = xr[lane];
  float4 pw = pr[lane];
  float d = xv.x * pw.x + xv.y * pw.y + xv.z * pw.z + xv.w * pw.w;
  #pragma unroll
  for (int off = 32; off > 0; off >>= 1) d += __shfl_down(d, off, 64);
  if (lane == 0) y[row] = d * s_inv;
}

// ---------------- exact top-k via radix-256 select ----------------
// rank[i] = position among kept nodes in ascending-index order, or -1.
// Ties at threshold keep lowest indices (matches top_k stability + sort).

__device__ __forceinline__ unsigned block_exscan_fast(unsigned tv, unsigned* wred,
                                                      int tid, int lane, int wid) {
  unsigned v = tv;
  #pragma unroll
  for (int o = 1; o < 64; o <<= 1) {
    unsigned n = __shfl_up(v, o, 64);
    if (lane >= o) v += n;
  }
  if (lane == 63) wred[wid] = v;
  __syncthreads();
  unsigned off = 0;
  #pragma unroll
  for (int w = 0; w < 16; ++w) off += (w < wid) ? wred[w] : 0u;
  __syncthreads();  // wred reused by caller / next call
  return off + v - tv;
}

__global__ __launch_bounds__(1024) void topk_radix(const float* __restrict__ y,
                                                   int* __restrict__ rank) {
  __shared__ unsigned keys[N_NODES];     // 32 KB
  __shared__ unsigned histw[256 * 16];   // 16 KB wave-private histograms
  __shared__ unsigned wred[16];
  __shared__ unsigned s_pref, s_krem;
  const int tid = threadIdx.x;
  const int lane = tid & 63;
  const int wid = tid >> 6;
  for (int i = tid; i < N_NODES; i += 1024) {
    unsigned u = __float_as_uint(y[i]);
    keys[i] = (u & 0x80000000u) ? ~u : (u | 0x80000000u);  // monotone map
  }
  if (tid == 0) { s_pref = 0u; s_krem = (unsigned)K_SEL; }
  __syncthreads();

  // 4 passes over 8-bit digits, MSB first.
  #pragma unroll 1
  for (int shift = 24; shift >= 0; shift -= 8) {
    #pragma unroll
    for (int i = 0; i < 4; ++i) histw[tid + i * 1024] = 0u;
    const unsigned pref = s_pref;
    const unsigned krem = s_krem;
    __syncthreads();
    const unsigned pmask = (shift == 24) ? 0u : (0xFFFFFFFFu << (shift + 8));
    for (int i = tid; i < N_NODES; i += 1024) {
      unsigned k = keys[i];
      if ((k & pmask) == pref)
        atomicAdd(&histw[(((k >> shift) & 255u) << 4) + wid], 1u);
    }
    __syncthreads();
    unsigned hb = 0, v = 0;
    if (tid < 256) {
      const int b = 255 - tid;
      #pragma unroll
      for (int w = 0; w < 16; ++w) hb += histw[(b << 4) + w];
      v = hb;
    }
    #pragma unroll
    for (int o = 1; o < 64; o <<= 1) {
      unsigned n = __shfl_up(v, o, 64);
      if (lane >= o) v += n;
    }
    if (tid < 256 && lane == 63) wred[wid] = v;
    __syncthreads();
    if (tid < 256) {
      unsigned off = 0;
      #pragma unroll
      for (int w = 0; w < 4; ++w) off += (w < wid) ? wred[w] : 0u;
      const unsigned cge = v + off;              // #(prefix match, digit >= b)
      const unsigned b = 255u - (unsigned)tid;
      const unsigned cgt = cge - hb;             // #(prefix match, digit > b)
      if (cgt < krem && cge >= krem) {           // unique winning bucket
        s_pref = pref | (b << shift);
        s_krem = krem - cgt;
      }
    }
    __syncthreads();
  }

  const unsigned T = s_pref;        // exact K-th largest key value
  const unsigned need_eq = s_krem;  // how many ==T keys to keep (lowest idx)

  const int base = tid << 3;
  unsigned e[8], g[8], te = 0;
  #pragma unroll
  for (int j = 0; j < 8; ++j) {
    unsigned k = keys[base + j];
    e[j] = (k == T) ? 1u : 0u;
    g[j] = (k > T) ? 1u : 0u;
    te += e[j];
  }
  unsigned eqr = block_exscan_fast(te, wred, tid, lane, wid);
  unsigned keep[8], tk = 0;
  #pragma unroll
  for (int j = 0; j < 8; ++j) {
    unsigned kp = g[j] | (e[j] & ((eqr < need_eq) ? 1u : 0u));
    eqr += e[j];
    keep[j] = kp;
    tk += kp;
  }
  unsigned pos = block_exscan_fast(tk, wred, tid, lane, wid);
  #pragma unroll
  for (int j = 0; j < 8; ++j) {
    if (keep[j]) { rank[base + j] = (int)pos; pos++; }
    else rank[base + j] = -1;
  }
}

// ---------------- fused gather -> fp8: one pass over A ----------------
// Abf8[rank[r], c] = e4m3(A[r, c])   (selected rows, K contiguous)
// Bt8 [rank[c], r] = e4m3(A[r, c])   (selected cols, transposed)
__global__ __launch_bounds__(256) void gather_both(const float* __restrict__ A,
                                                   const int* __restrict__ rank,
                                                   unsigned char* __restrict__ Abf8,
                                                   unsigned char* __restrict__ Bt8) {
  __shared__ float tile[64][68];   // pad 68: rows 16B-aligned, col reads ~2-way
  __shared__ int rr_[64], rc_[64];
  const int tid = threadIdx.x;
  const int r0 = blockIdx.y << 6, c0 = blockIdx.x << 6;
  if (tid < 64) rr_[tid] = rank[r0 + tid];
  else if (tid < 128) rc_[tid - 64] = rank[c0 + tid - 64];
  const int trow = tid >> 4, tc4 = (tid & 15) << 2;
  #pragma unroll
  for (int i = 0; i < 4; ++i) {
    const float4 v = *(const float4*)(A + (size_t)(r0 + trow + i * 16) * N_NODES + c0 + tc4);
    *(float4*)&tile[trow + i * 16][tc4] = v;
  }
  __syncthreads();
  // rows -> Abf8: one 16B store per thread (row tid>>2, 16 cols at (tid&3)*16)
  {
    const int tr = tid >> 2, qc = (tid & 3) << 4;
    const int rk = rr_[tr];
    if (rk >= 0) {
      intx4 o;
      #pragma unroll
      for (int jj = 0; jj < 4; ++jj) {
        float4 f = *(const float4*)&tile[tr][qc + jj * 4];
        int v = __builtin_amdgcn_cvt_pk_fp8_f32(f.x, f.y, 0, false);
        v = __builtin_amdgcn_cvt_pk_fp8_f32(f.z, f.w, v, true);
        o[jj] = v;
      }
      *(intx4*)(Abf8 + (size_t)rk * N_NODES + c0 + qc) = o;
    }
  }
  // cols -> Bt8: one 16B store per thread (col tid>>2, 16 rows at (tid&3)*16)
  {
    const int tc = tid >> 2, qr = (tid & 3) << 4;
    const int rk = rc_[tc];
    if (rk >= 0) {
      intx4 o;
      #pragma unroll
      for (int jj = 0; jj < 4; ++jj) {
        float a0 = tile[qr + jj * 4 + 0][tc];
        float a1 = tile[qr + jj * 4 + 1][tc];
        float a2 = tile[qr + jj * 4 + 2][tc];
        float a3 = tile[qr + jj * 4 + 3][tc];
        int v = __builtin_amdgcn_cvt_pk_fp8_f32(a0, a1, 0, false);
        v = __builtin_amdgcn_cvt_pk_fp8_f32(a2, a3, v, true);
        o[jj] = v;
      }
      *(intx4*)(Bt8 + (size_t)rk * N_NODES + r0 + qr) = o;
    }
  }
}

// ---------------- X_pooled[rank[i],:] = X[i,:] * tanh(y[i]) ----------------
__global__ __launch_bounds__(256) void x_pool(const float* __restrict__ X,
                                              const float* __restrict__ y,
                                              const int* __restrict__ rank,
                                              float* __restrict__ out0) {
  const int i = blockIdx.x;
  const int r = rank[i];
  if (r < 0) return;
  const float g = tanhf(y[i]);
  out0[(size_t)r * F_DIM + threadIdx.x] = X[(size_t)i * F_DIM + threadIdx.x] * g;
}

// ---------------- C[m,n] = sum_k A8[m,k] * B8[n,k] (fp8 MX, scale=1.0) ----
// 256x256 block, 512 threads (8 waves, 4M x 2N grid), wave tile 64x128.
// K-slab 128B: per round 16 MFMA/wave (2200cy/CU) vs LDS 256KB (2000cy) with
// ONE barrier-pair -> fixed cost amortized 2x vs R7. Ring-2 x 64KB = 128KB.
// Row = 128B = 8 subchunks of 16B; swizzle s' = s ^ (row&7) on both the
// staging global source and the ds_read address (8 consecutive rows -> all 8
// bank-quads). Compute phased per K-half to bound VGPR.
#define SLOT 65536  // one slot: A 32KB @ +0, B 32KB @ +32768

#define G_ISSUE(t)                                                              \
  {                                                                             \
    const int ko_ = (t) * 128, rs_ = ((t) & 1) * SLOT;                          \
    _Pragma("unroll")                                                           \
    for (int j = 0; j < 8; ++j)                                                 \
      async_copy16(gsrc[j] + ko_, (char*)lds + rs_ + ldst[j]);                  \
  }

__global__ __launch_bounds__(512, 2) void gemm_fp8(const unsigned char* __restrict__ A,
                                                   const unsigned char* __restrict__ B,
                                                   float* __restrict__ C) {
  const int Kd = N_NODES;  // 8192
  const int Nd = K_SEL;    // 4096
  __shared__ unsigned char lds[2 * SLOT];  // 128 KB
  const int tid = threadIdx.x;
  const int wave = tid >> 6, lane = tid & 63;
  // XCD-chunked swizzle: 256 blocks (16x16 tiles); XCD x owns m-tiles
  // {2x, 2x+1} (512 rows x 8KB fp8 = 4MB = L2-resident A panel), streams n.
  const int wg = blockIdx.y * gridDim.x + blockIdx.x;
  const int xcd = wg & 7, loc = wg >> 3;          // loc in [0,32)
  const int m0 = (xcd * 2 + (loc & 1)) * 256;
  const int n0 = (loc >> 1) * 256;
  const int wm = (wave >> 1) * 64;                // 4 M-groups of 64
  const int wn = (wave & 1) * 128;                // 2 N-groups of 128
  const int l31 = lane & 31, lh = lane >> 5;

  // staging: j in {0..3} -> A quarters, {4..7} -> B quarters.
  // Slot L = (j&3)*512 + tid: row = L>>3 in [0,256), phys subchunk L&7,
  // logical s = (L&7) ^ (row&7). LDS dest linear (wave base + lane*16);
  // swizzle applied on the global source address.
  const unsigned char* gsrc[8];
  int ldst[8];
  #pragma unroll
  for (int j = 0; j < 8; ++j) {
    const int L = (j & 3) * 512 + tid;
    const int row = L >> 3;
    const int s = (L & 7) ^ (row & 7);
    const unsigned char* base =
        (j < 4) ? (A + (size_t)(m0 + row) * Kd) : (B + (size_t)(n0 + row) * Kd);
    gsrc[j] = base + s * 16;
    ldst[j] = ((j < 4) ? 0 : 32768) + (j & 3) * 8192 + wave * 1024;
  }

  // fragment ds_read offsets: lane row = l31 (+group), K-half kh, then
  // j16 = kh*4 + lh*2 + h; phys = j16 ^ (row&7).
  int offA[2][2][2], offB[2][4][2];
  #pragma unroll
  for (int kh = 0; kh < 2; ++kh) {
    #pragma unroll
    for (int f = 0; f < 2; ++f) {
      const int ra = wm + f * 32 + l31;
      #pragma unroll
      for (int h = 0; h < 2; ++h)
        offA[kh][f][h] = ra * 128 + (((kh * 4 + lh * 2 + h) ^ (ra & 7)) << 4);
    }
    #pragma unroll
    for (int g = 0; g < 4; ++g) {
      const int rb = wn + g * 32 + l31;
      #pragma unroll
      for (int h = 0; h < 2; ++h)
        offB[kh][g][h] = 32768 + rb * 128 + (((kh * 4 + lh * 2 + h) ^ (rb & 7)) << 4);
    }
  }

  floatx16 acc[2][4] = {};

  G_ISSUE(0);
  #pragma unroll 1
  for (int t = 0; t < 64; ++t) {
    if (t < 63) {
      G_ISSUE(t + 1);
      asm volatile("s_waitcnt vmcnt(8)" ::: "memory");   // slab t's 8 done
    } else {
      asm volatile("s_waitcnt vmcnt(0)" ::: "memory");
    }
    __builtin_amdgcn_s_barrier();
    asm volatile("" ::: "memory");

    const char* bp = (const char*)lds + (t & 1) * SLOT;
    #pragma unroll
    for (int kh = 0; kh < 2; ++kh) {
      intx8 av[2], bv[4];
      #pragma unroll
      for (int f = 0; f < 2; ++f) {
        intx4 lo = *(const intx4*)(bp + offA[kh][f][0]);
        intx4 hi = *(const intx4*)(bp + offA[kh][f][1]);
        av[f] = __builtin_shufflevector(lo, hi, 0, 1, 2, 3, 4, 5, 6, 7);
      }
      #pragma unroll
      for (int g = 0; g < 4; ++g) {
        intx4 lo = *(const intx4*)(bp + offB[kh][g][0]);
        intx4 hi = *(const intx4*)(bp + offB[kh][g][1]);
        bv[g] = __builtin_shufflevector(lo, hi, 0, 1, 2, 3, 4, 5, 6, 7);
      }
      __builtin_amdgcn_s_setprio(1);
      #pragma unroll
      for (int tm = 0; tm < 2; ++tm)
        #pragma unroll
        for (int tn = 0; tn < 4; ++tn)
          acc[tm][tn] = __builtin_amdgcn_mfma_scale_f32_32x32x64_f8f6f4(
              av[tm], bv[tn], acc[tm][tn], 0, 0, 0, 0x7F7F7F7F, 0, 0x7F7F7F7F);
      __builtin_amdgcn_s_setprio(0);
    }
    asm volatile("s_waitcnt lgkmcnt(0)" ::: "memory");   // slot-lifetime safety
    __builtin_amdgcn_s_barrier();
    asm volatile("" ::: "memory");
  }

  // C/D 32x32: col = lane&31, row = (reg&3) + 8*(reg>>2) + 4*(lane>>5)
  #pragma unroll
  for (int tm = 0; tm < 2; ++tm)
    #pragma unroll
    for (int tn = 0; tn < 4; ++tn) {
      float* cp = C + (size_t)(m0 + wm + tm * 32) * Nd + n0 + wn + tn * 32 + l31;
      #pragma unroll
      for (int r = 0; r < 16; ++r) {
        const int crow = (r & 3) + 8 * (r >> 2) + 4 * lh;
        cp[(size_t)crow * Nd] = acc[tm][tn][r];
      }
    }
}

extern "C" void kernel_launch(void* const* d_in, const int* in_sizes, int n_in,
                              void* d_out, int out_size, void* d_ws, size_t ws_size,
                              hipStream_t stream) {
  const float* X = (const float*)d_in[0];
  const float* A = (const float*)d_in[1];
  const float* p = (const float*)d_in[2];
  float* out0 = (float*)d_out;                      // X_pooled 4096x256
  float* out1 = out0 + (size_t)K_SEL * F_DIM;       // A_pooled 4096x4096

  // ws layout: y (32KB) | rank (32KB) | Abf8 (32MB) | Bt8 (32MB)
  char* ws = (char*)d_ws;
  float* y = (float*)ws;
  int* rank = (int*)(ws + 32768);
  unsigned char* Abf8 = (unsigned char*)(ws + 65536);
  unsigned char* Bt8 = Abf8 + (size_t)K_SEL * N_NODES;

  compute_y<<<N_NODES / 4, 256, 0, stream>>>(X, p, y);
  topk_radix<<<1, 1024, 0, stream>>>(y, rank);
  x_pool<<<N_NODES, 256, 0, stream>>>(X, y, rank, out0);
  gather_both<<<dim3(N_NODES / 64, N_NODES / 64), 256, 0, stream>>>(A, rank, Abf8, Bt8);
  gemm_fp8<<<dim3(K_SEL / 256, K_SEL / 256), 512, 0, stream>>>(Abf8, Bt8, out1);
}